// Round 15
// baseline (80.859 us; speedup 1.0000x reference)
//
#include <hip/hip_runtime.h>
#include <hip/hip_bf16.h>
#include <stdint.h>

typedef __attribute__((ext_vector_type(8))) short bf16x8;
typedef __attribute__((ext_vector_type(4))) float f32x4;
typedef __attribute__((ext_vector_type(4))) unsigned u32x4;
typedef __attribute__((ext_vector_type(2))) unsigned u32x2;

#define NT 256

// ---------------- ws layout (bytes) ----------------
#define WS_CE    0
#define WS_PR1   16384
#define WS_PR2   24576
#define WS_CR1   57344
#define WS_CR2   90112
#define WS_CR3   106496
#define WS_SY1   108544
#define WS_SY2   112640
#define WS_SP1   114688
#define WS_SP2   196608
#define WS_SP3   360448

// ---------------- helpers ----------------

__device__ __forceinline__ short bf1(float x) {
    unsigned u = __float_as_uint(x);
    return (short)((u + 0x7fffu + ((u >> 16) & 1u)) >> 16);
}
__device__ __forceinline__ float bfval(short h) {
    return __uint_as_float(((unsigned)(unsigned short)h) << 16);
}
// two f32 -> packed bf16 dword via v_cvt_pk_bf16_f32 (no builtin on gfx950)
__device__ __forceinline__ unsigned cvtpk(float lo, float hi) {
    unsigned r;
    asm("v_cvt_pk_bf16_f32 %0, %1, %2" : "=v"(r) : "v"(lo), "v"(hi));
    return r;
}

template<int CTRL>
__device__ __forceinline__ float dpp_add(float v) {
    int o = __builtin_amdgcn_mov_dpp(__float_as_int(v), CTRL, 0xf, 0xf, true);
    return v + __int_as_float(o);
}
__device__ __forceinline__ float row16_sum(float v) {
    v = dpp_add<0x128>(v);
    v = dpp_add<0x124>(v);
    v = dpp_add<0x122>(v);
    v = dpp_add<0x121>(v);
    return v;
}

// ---- cooperative stage: BYTES from global into LDS (linear, 16B/lane async) ----
template<int BYTES>
__device__ __forceinline__ void stage(const char* __restrict__ gsrc, char* ldsdst, int t) {
    const int wu = (t >> 6) << 10;   // wave-uniform LDS base offset (HW adds lane*16)
#pragma unroll
    for (int i = 0; i < BYTES / 4096; ++i)
        __builtin_amdgcn_global_load_lds(
            (const __attribute__((address_space(1))) void*)(gsrc + i * 4096 + t * 16),
            (__attribute__((address_space(3))) void*)(ldsdst + i * 4096 + wu),
            16, 0, 0);
}

// ---- flat accumulator file: acc[f] = row-frag0, acc[8+f] = row-frag1 ----
template<int NF>
__device__ __forceinline__ void init_acc(f32x4* acc, const float* __restrict__ bias, int c) {
#pragma unroll
    for (int f = 0; f < NF; ++f) {
        const float bv = bias[f * 16 + c];
        acc[f]     = (f32x4){bv, bv, bv, bv};
        acc[8 + f] = (f32x4){bv, bv, bv, bv};
    }
}
__device__ __forceinline__ void init_b3(f32x4& a0, f32x4& a1, const float* __restrict__ b3, int c) {
    const float bv = (c < 3) ? b3[c] : 0.f;
    a0 = (f32x4){bv, bv, bv, bv};
    a1 = (f32x4){bv, bv, bv, bv};
}

// ---- A fragment from xyz registers (k=0..2 hi, k=3..5 lo of the bf16 split) ----
__device__ __forceinline__ bf16x8 mkA6(float a0, float a1, float a2, bool active) {
    bf16x8 A = (bf16x8){0, 0, 0, 0, 0, 0, 0, 0};
    if (active) {
        const short h0 = bf1(a0), h1 = bf1(a1), h2 = bf1(a2);
        A[0] = h0; A[1] = h1; A[2] = h2;
        A[3] = bf1(a0 - bfval(h0));
        A[4] = bf1(a1 - bfval(h1));
        A[5] = bf1(a2 - bfval(h2));
    }
    return A;
}

// ---- MFMA with A from registers (single K-step), B frags from global ----
template<int NF>
__device__ __forceinline__ void mfma_reg(bf16x8 A0, bf16x8 A1, const char* __restrict__ Bg,
                                         int lane, f32x4* acc) {
#pragma unroll
    for (int f = 0; f < NF; ++f) {
        bf16x8 B = *(const bf16x8*)(Bg + f * 1024 + lane * 16);
        acc[f]     = __builtin_amdgcn_mfma_f32_16x16x32_bf16(A0, B, acc[f], 0, 0, 0);
        acc[8 + f] = __builtin_amdgcn_mfma_f32_16x16x32_bf16(A1, B, acc[8 + f], 0, 0, 0);
    }
}

// ---- staged MFMA layer: B frags double-buffered through LDS wb (2 x 4KB halves).
//      NF=8 splits each ks-chunk into two 4-frag sub-chunks; sub-chunk 0 must
//      already be staged into wb[0] by the caller (prefetch). ----
template<int NF, int KS>
__device__ __forceinline__ void mfma_staged(const char* actb, char* wb,
                                            const char* __restrict__ Bg,
                                            int R0c, int g, int lane, int t, f32x4* acc) {
    constexpr int H  = (NF == 8) ? 2 : 1;       // sub-chunks per ks
    constexpr int FH = NF / H;                  // frags per sub-chunk (4)
    constexpr int CH = FH * 1024;               // 4096 bytes
    constexpr int P  = KS * H;                  // total sub-chunks
    const int swz = (R0c & 7) << 4;
    __syncthreads();                            // drain prefetched sub-chunk 0
#pragma unroll
    for (int p = 0; p < P; ++p) {
        if (p + 1 < P)
            stage<CH>(Bg + (p + 1) * CH, wb + ((p + 1) & 1) * 4096, t);
        const char* cur = wb + (p & 1) * 4096;
        const int ks = p / H;
        const int h  = p % H;
        const int kb = ks * 64 + g * 16;
        bf16x8 A0 = *(const bf16x8*)(actb + ((R0c * 256 + kb) ^ swz));
        bf16x8 A1 = *(const bf16x8*)(actb + (((R0c + 16) * 256 + kb) ^ swz));
#pragma unroll
        for (int f = 0; f < FH; ++f) {
            const int fh = h * FH + f;
            bf16x8 B = *(const bf16x8*)(cur + f * 1024 + lane * 16);
            acc[fh]     = __builtin_amdgcn_mfma_f32_16x16x32_bf16(A0, B, acc[fh], 0, 0, 0);
            acc[8 + fh] = __builtin_amdgcn_mfma_f32_16x16x32_bf16(A1, B, acc[8 + fh], 0, 0, 0);
        }
        __syncthreads();                        // next sub-chunk staged & cur's sibling free
    }
}

// ---- N=3 projection (K=64, KS=2), unstaged ----
__device__ __forceinline__ void mfma3(const char* actb, const char* __restrict__ Bg,
                                      int R0c, int g, int lane, f32x4& a0, f32x4& a1) {
    const int swz = (R0c & 7) << 4;
#pragma unroll
    for (int ks = 0; ks < 2; ++ks) {
        const int kb = ks * 64 + g * 16;
        bf16x8 A0 = *(const bf16x8*)(actb + ((R0c * 256 + kb) ^ swz));
        bf16x8 A1 = *(const bf16x8*)(actb + (((R0c + 16) * 256 + kb) ^ swz));
        bf16x8 B = *(const bf16x8*)(Bg + ks * 1024 + lane * 16);
        a0 = __builtin_amdgcn_mfma_f32_16x16x32_bf16(A0, B, a0, 0, 0, 0);
        a1 = __builtin_amdgcn_mfma_f32_16x16x32_bf16(A1, B, a1, 0, 0, 0);
    }
}

// ---- LayerNorm + LeakyReLU, vectorized over the 4 row-quads ----
template<int NF>
__device__ __forceinline__ void ln_lrelu_frag(f32x4* acc, int c,
                                              const float* __restrict__ g,
                                              const float* __restrict__ be, float invN) {
    float gv[NF], bev[NF];
#pragma unroll
    for (int f = 0; f < NF; ++f) { gv[f] = g[f * 16 + c]; bev[f] = be[f * 16 + c]; }
#pragma unroll
    for (int rf = 0; rf < 2; ++rf) {
        f32x4 s1 = acc[rf * 8];
        f32x4 s2 = acc[rf * 8] * acc[rf * 8];
#pragma unroll
        for (int f = 1; f < NF; ++f) {
            s1 += acc[rf * 8 + f];
            s2 += acc[rf * 8 + f] * acc[rf * 8 + f];
        }
#pragma unroll
        for (int q = 0; q < 4; ++q) { s1[q] = row16_sum(s1[q]); s2[q] = row16_sum(s2[q]); }
        const f32x4 mu = s1 * invN;
        f32x4 ri;
#pragma unroll
        for (int q = 0; q < 4; ++q)
            ri[q] = rsqrtf(fmaf(s2[q], invN, -mu[q] * mu[q]) + 1e-5f);
#pragma unroll
        for (int f = 0; f < NF; ++f) {
            f32x4 x = (acc[rf * 8 + f] - mu) * ri;
            x = x * gv[f] + bev[f];
            acc[rf * 8 + f] = __builtin_elementwise_max(x, 0.2f * x);
        }
    }
}

// ---- pack to LDS act tile. Storage map (dword D within row, lane c):
//   NF=8: D = c*4+d holds cols (d*16+c, (d+4)*16+c)   -> one b128/row/thread
//   NF=4: D = c*2+d holds cols (d*16+c, (d+2)*16+c)   -> one b64/row/thread
//  (B fragments are built with the matching k-map in wfrag) ----
template<int NF>
__device__ __forceinline__ void pack_store(char* dst, f32x4* acc, int R0, int c, int g) {
#pragma unroll
    for (int rf = 0; rf < 2; ++rf)
#pragma unroll
        for (int q = 0; q < 4; ++q) {
            const int row = R0 + rf * 16 + g * 4 + q;
            const int swz = (row & 7) << 4;
            if constexpr (NF == 8) {
                u32x4 v;
                v.x = cvtpk(acc[rf * 8 + 0][q], acc[rf * 8 + 4][q]);
                v.y = cvtpk(acc[rf * 8 + 1][q], acc[rf * 8 + 5][q]);
                v.z = cvtpk(acc[rf * 8 + 2][q], acc[rf * 8 + 6][q]);
                v.w = cvtpk(acc[rf * 8 + 3][q], acc[rf * 8 + 7][q]);
                *(u32x4*)(dst + ((row * 256 + c * 16) ^ swz)) = v;
            } else {
                u32x2 v;
                v.x = cvtpk(acc[rf * 8 + 0][q], acc[rf * 8 + 2][q]);
                v.y = cvtpk(acc[rf * 8 + 1][q], acc[rf * 8 + 3][q]);
                *(u32x2*)(dst + ((row * 256 + c * 8) ^ swz)) = v;
            }
        }
}

// ---------------- prep kernels ----------------

__global__ void ce_precompute_kernel(const int* __restrict__ cats,
                                     const float* __restrict__ cat_emb,
                                     const float* __restrict__ cr_w1,
                                     const float* __restrict__ cr_b1,
                                     float* __restrict__ ce_out) {
    const int bb = blockIdx.x;
    const int j = threadIdx.x;            // 0..127
    const int c = cats[bb];
    float acc = cr_b1[j];
#pragma unroll 4
    for (int k = 0; k < 128; ++k)
        acc = fmaf(cat_emb[c * 128 + k], cr_w1[(128 + k) * 128 + j], acc);
    ce_out[bb * 128 + j] = acc;
}

// build all B-fragments, ks-major; k-maps match the b128/b64 act storage:
//   mode 1 (128-col input): k = ((e>>1) + 4*(e&1))*16 + ks*4 + g
//   mode 2 (64-col input) : k = ((e>>1 & 1) + 2*(e&1))*16 + ks*8 + g*2 + (e>>2)
//   mode 0 (register A)   : k = p (identity, only k<6 nonzero)
__global__ void wfrag_kernel(
    const float* __restrict__ pr_w1, const float* __restrict__ pr_w2,
    const float* __restrict__ cr_w1, const float* __restrict__ cr_w2,
    const float* __restrict__ cr_w3, const float* __restrict__ sy_w1,
    const float* __restrict__ sy_w2, const float* __restrict__ sp_w1,
    const float* __restrict__ sp_w2, const float* __restrict__ sp_w3,
    char* __restrict__ ws)
{
    const int id = blockIdx.x * 256 + threadIdx.x;   // 0..22783 frag-lanes
    int local, NF, base, cat = 0;
    const float* W = nullptr;
    int mode;
    int Nstride = 0;

    if (id < 512)        { local = id;          NF = 8; base = WS_PR1; W = pr_w1; mode = 0; Nstride = 128; }
    else if (id < 2560)  { local = id - 512;    NF = 8; base = WS_PR2; W = pr_w2; mode = 1; Nstride = 128; }
    else if (id < 4608)  { local = id - 2560;   NF = 8; base = WS_CR1; W = cr_w1; mode = 1; Nstride = 128; }
    else if (id < 5632)  { local = id - 4608;   NF = 4; base = WS_CR2; W = cr_w2; mode = 1; Nstride = 64; }
    else if (id < 5760)  { local = id - 5632;   NF = 1; base = WS_CR3; W = cr_w3; mode = 2; }
    else if (id < 6016)  { local = id - 5760;   NF = 4; base = WS_SY1; W = sy_w1; mode = 0; Nstride = 64; }
    else if (id < 6144)  { local = id - 6016;   NF = 1; base = WS_SY2; W = sy_w2; mode = 2; }
    else if (id < 11264) { int r = id - 6144;  cat = r / 512;  local = r % 512;
                           NF = 8; base = WS_SP1 + cat * 8192;  W = sp_w1 + cat * 384;  mode = 0; Nstride = 128; }
    else if (id < 21504) { int r = id - 11264; cat = r / 1024; local = r % 1024;
                           NF = 4; base = WS_SP2 + cat * 16384; W = sp_w2 + cat * 8192; mode = 1; Nstride = 64; }
    else                 { int r = id - 21504; cat = r / 128;  local = r % 128;
                           NF = 1; base = WS_SP3 + cat * 2048;  W = sp_w3 + cat * 192;  mode = 2; }

    const int lane = local & 63;
    const int fk = local >> 6;
    const int f = fk % NF;              // ks-major: chunk = all f of one ks
    const int ks = fk / NF;
    const int c = lane & 15;
    const int g = lane >> 4;
    const int n = f * 16 + c;

    bf16x8 H;
#pragma unroll
    for (int e = 0; e < 8; ++e) {
        float v = 0.f;
        if (mode == 0) {
            const int p = ks * 32 + g * 8 + e;
            if (p < 6) v = W[(p < 3 ? p : p - 3) * Nstride + n];
        } else if (mode == 1) {
            const int k = ((e >> 1) + 4 * (e & 1)) * 16 + ks * 4 + g;
            v = W[k * Nstride + n];
        } else {
            const int k = (((e >> 1) & 1) + 2 * (e & 1)) * 16 + ks * 8 + g * 2 + (e >> 2);
            if (n < 3) v = W[k * 3 + n];
        }
        H[e] = bf1(v);
    }
    *(bf16x8*)(ws + base + local * 16) = H;
}

// ---------------- main fused kernel ----------------

__global__ __launch_bounds__(NT, 3)
void shape_refine_mfma13(
    const float* __restrict__ points, const int* __restrict__ cats,
    const float* __restrict__ pr_b1, const float* __restrict__ pr_g1, const float* __restrict__ pr_be1,
    const float* __restrict__ pr_b2, const float* __restrict__ pr_g2, const float* __restrict__ pr_be2,
    const float* __restrict__ cr_g1, const float* __restrict__ cr_be1,
    const float* __restrict__ cr_b2, const float* __restrict__ cr_g2, const float* __restrict__ cr_be2,
    const float* __restrict__ cr_b3,
    const float* __restrict__ sy_b1, const float* __restrict__ sy_g1, const float* __restrict__ sy_be1,
    const float* __restrict__ sy_b2,
    const float* __restrict__ sp_b1, const float* __restrict__ sp_g1, const float* __restrict__ sp_be1,
    const float* __restrict__ sp_b2, const float* __restrict__ sp_g2, const float* __restrict__ sp_be2,
    const float* __restrict__ sp_b3,
    const char* __restrict__ ws,
    float* __restrict__ out)
{
    __shared__ char act[32768];    // bf16 [128 rows][128 cols]; rows R0..R0+31 private to wave wid
    __shared__ char wb[8192];      // B-frag staging, 2 x 4KB halves (40KB total -> 4 blocks/CU)

    const int t = threadIdx.x;
    const int lane = t & 63;
    const int wid = t >> 6;
    const int c = lane & 15;
    const int g = lane >> 4;
    const int R0 = wid * 32;
    const int R0c = R0 + c;

    const int bid = blockIdx.x;
    const int batch = bid >> 6;              // 64 blocks (tiles) per batch
    const int pbase = batch * 8192 + (bid & 63) * 128;

    const int cat = __builtin_amdgcn_readfirstlane(cats[batch]);
    const bool sym = (cat == 2) || (cat == 8);

    // prefetch P2 sub-chunk0 under P1's compute
    stage<4096>(ws + WS_PR2, wb, t);

    // xyz for this lane's two A-rows (rows R0c and R0c+16)
    const float* p0 = points + 3 * (pbase + R0c);
    const float x0 = p0[0], x1 = p0[1], x2 = p0[2];
    const float y0 = p0[48], y1 = p0[49], y2 = p0[50];

    const bf16x8 A0 = mkA6(x0, x1, x2, g == 0);
    const bf16x8 A1 = mkA6(y0, y1, y2, g == 0);

    f32x4 acc[16];
    f32x4 ocr0, ocr1, oo0, oo1;

    // ---- P1: pr1 (3->128) from registers ----
    init_acc<8>(acc, pr_b1, c);
    mfma_reg<8>(A0, A1, ws + WS_PR1, lane, acc);
    ln_lrelu_frag<8>(acc, c, pr_g1, pr_be1, 1.f / 128.f);
    pack_store<8>(act, acc, R0, c, g);

    // ---- P2: pr2 (128->128), staged ----
    init_acc<8>(acc, pr_b2, c);
    mfma_staged<8, 4>(act, wb, ws + WS_PR2, R0c, g, lane, t, acc);
    stage<4096>(ws + WS_CR1, wb, t);            // prefetch P3 sub-chunk0 under LN
    ln_lrelu_frag<8>(acc, c, pr_g2, pr_be2, 1.f / 128.f);
    pack_store<8>(act, acc, R0, c, g);

    // ---- P3: cr1 (256->128, cat-emb folded into per-batch bias), staged ----
    init_acc<8>(acc, (const float*)(ws + WS_CE) + batch * 128, c);
    mfma_staged<8, 4>(act, wb, ws + WS_CR1, R0c, g, lane, t, acc);
    stage<4096>(ws + WS_CR2, wb, t);            // prefetch P4 sub-chunk0 under LN
    ln_lrelu_frag<8>(acc, c, cr_g1, cr_be1, 1.f / 128.f);
    pack_store<8>(act, acc, R0, c, g);

    // ---- P4: cr2 (128->64), staged ----
    init_acc<4>(acc, cr_b2, c);
    mfma_staged<4, 4>(act, wb, ws + WS_CR2, R0c, g, lane, t, acc);
    stage<4096>(ws + WS_SP2 + cat * 16384, wb, t);  // prefetch P6 sub-chunk0 under P4-LN + P5
    ln_lrelu_frag<4>(acc, c, cr_g2, cr_be2, 1.f / 64.f);
    pack_store<4>(act, acc, R0, c, g);

    // ---- P5: cr3 (64->3) + sp1 (3->128) ----
    init_b3(ocr0, ocr1, cr_b3, c);
    mfma3(act, ws + WS_CR3, R0c, g, lane, ocr0, ocr1);

    init_acc<8>(acc, sp_b1 + cat * 128, c);
    mfma_reg<8>(A0, A1, ws + WS_SP1 + cat * 8192, lane, acc);
    ln_lrelu_frag<8>(acc, c, sp_g1 + cat * 128, sp_be1 + cat * 128, 1.f / 128.f);
    pack_store<8>(act, acc, R0, c, g);

    // ---- P6: sp2 (128->64), staged ----
    init_acc<4>(acc, sp_b2 + cat * 64, c);
    mfma_staged<4, 4>(act, wb, ws + WS_SP2 + cat * 16384, R0c, g, lane, t, acc);
    ln_lrelu_frag<4>(acc, c, sp_g2 + cat * 64, sp_be2 + cat * 64, 1.f / 64.f);
    pack_store<4>(act, acc, R0, c, g);

    // ---- P7: sp3 (64->3), combine ----
    init_b3(oo0, oo1, sp_b3 + cat * 3, c);
    mfma3(act, ws + WS_SP3 + cat * 2048, R0c, g, lane, oo0, oo1);
    oo0 = ocr0 + 0.5f * oo0;
    oo1 = ocr1 + 0.5f * oo1;

    // ---- symmetry branch (block-uniform) ----
    if (sym) {
        init_acc<4>(acc, sy_b1, c);
        const bf16x8 S0 = mkA6(-x0, x1, x2, g == 0);
        const bf16x8 S1 = mkA6(-y0, y1, y2, g == 0);
        mfma_reg<4>(S0, S1, ws + WS_SY1, lane, acc);
        ln_lrelu_frag<4>(acc, c, sy_g1, sy_be1, 1.f / 64.f);
        pack_store<4>(act, acc, R0, c, g);
        f32x4 s0, s1;
        init_b3(s0, s1, sy_b2, c);
        mfma3(act, ws + WS_SY2, R0c, g, lane, s0, s1);
        const float flip = (c == 0) ? -1.f : 1.f;
#pragma unroll
        for (int q = 0; q < 4; ++q) {
            oo0[q] = (oo0[q] + flip * s0[q]) * 0.5f;
            oo1[q] = (oo1[q] + flip * s1[q]) * 0.5f;
        }
    }

    // ---- store: lane c<3 holds dim c for rows R0 + g*4+q and +16 ----
    if (c < 3) {
#pragma unroll
        for (int q = 0; q < 4; ++q) {
            const int row0 = R0 + g * 4 + q;
            out[3 * (pbase + row0) + c] = oo0[q];
            out[3 * (pbase + row0 + 16) + c] = oo1[q];
        }
    }
}

// ---------------- launch ----------------

extern "C" void kernel_launch(void* const* d_in, const int* in_sizes, int n_in,
                              void* d_out, int out_size, void* d_ws, size_t ws_size,
                              hipStream_t stream) {
    const float* points  = (const float*)d_in[0];
    const int*   cats    = (const int*)  d_in[1];
    const float* pr_w1   = (const float*)d_in[2];
    const float* pr_b1   = (const float*)d_in[3];
    const float* pr_g1   = (const float*)d_in[4];
    const float* pr_be1  = (const float*)d_in[5];
    const float* pr_w2   = (const float*)d_in[6];
    const float* pr_b2   = (const float*)d_in[7];
    const float* pr_g2   = (const float*)d_in[8];
    const float* pr_be2  = (const float*)d_in[9];
    const float* cat_emb = (const float*)d_in[10];
    const float* cr_w1   = (const float*)d_in[11];
    const float* cr_b1   = (const float*)d_in[12];
    const float* cr_g1   = (const float*)d_in[13];
    const float* cr_be1  = (const float*)d_in[14];
    const float* cr_w2   = (const float*)d_in[15];
    const float* cr_b2   = (const float*)d_in[16];
    const float* cr_g2   = (const float*)d_in[17];
    const float* cr_be2  = (const float*)d_in[18];
    const float* cr_w3   = (const float*)d_in[19];
    const float* cr_b3   = (const float*)d_in[20];
    const float* sy_w1   = (const float*)d_in[21];
    const float* sy_b1   = (const float*)d_in[22];
    const float* sy_g1   = (const float*)d_in[23];
    const float* sy_be1  = (const float*)d_in[24];
    const float* sy_w2   = (const float*)d_in[25];
    const float* sy_b2   = (const float*)d_in[26];
    const float* sp_w1   = (const float*)d_in[27];
    const float* sp_b1   = (const float*)d_in[28];
    const float* sp_g1   = (const float*)d_in[29];
    const float* sp_be1  = (const float*)d_in[30];
    const float* sp_w2   = (const float*)d_in[31];
    const float* sp_b2   = (const float*)d_in[32];
    const float* sp_g2   = (const float*)d_in[33];
    const float* sp_be2  = (const float*)d_in[34];
    const float* sp_w3   = (const float*)d_in[35];
    const float* sp_b3   = (const float*)d_in[36];

    char* ws = (char*)d_ws;
    float* out = (float*)d_out;

    ce_precompute_kernel<<<dim3(32), dim3(128), 0, stream>>>(cats, cat_emb, cr_w1, cr_b1, (float*)ws);
    wfrag_kernel<<<dim3(89), dim3(256), 0, stream>>>(pr_w1, pr_w2, cr_w1, cr_w2, cr_w3,
                                                     sy_w1, sy_w2, sp_w1, sp_w2, sp_w3, ws);

    shape_refine_mfma13<<<dim3(2048), dim3(NT), 0, stream>>>(
        points, cats,
        pr_b1, pr_g1, pr_be1,
        pr_b2, pr_g2, pr_be2,
        cr_g1, cr_be1,
        cr_b2, cr_g2, cr_be2,
        cr_b3,
        sy_b1, sy_g1, sy_be1, sy_b2,
        sp_b1, sp_g1, sp_be1,
        sp_b2, sp_g2, sp_be2,
        sp_b3,
        ws, out);
}

// Round 16
// 77.236 us; speedup vs baseline: 1.0469x; 1.0469x over previous
//
#include <hip/hip_runtime.h>
#include <hip/hip_bf16.h>
#include <stdint.h>

typedef __attribute__((ext_vector_type(8))) short bf16x8;
typedef __attribute__((ext_vector_type(4))) float f32x4;
typedef __attribute__((ext_vector_type(4))) unsigned u32x4;
typedef __attribute__((ext_vector_type(2))) unsigned u32x2;

#define NT 256

// ---------------- ws layout (bytes) ----------------
#define WS_CE    0
#define WS_PR1   16384
#define WS_PR2   24576
#define WS_CR1   57344
#define WS_CR2   90112
#define WS_CR3   106496
#define WS_SY1   108544
#define WS_SY2   112640
#define WS_SP1   114688
#define WS_SP2   196608
#define WS_SP3   360448

// ---------------- helpers ----------------

__device__ __forceinline__ short bf1(float x) {
    unsigned u = __float_as_uint(x);
    return (short)((u + 0x7fffu + ((u >> 16) & 1u)) >> 16);
}
__device__ __forceinline__ float bfval(short h) {
    return __uint_as_float(((unsigned)(unsigned short)h) << 16);
}
// two f32 -> packed bf16 dword via v_cvt_pk_bf16_f32 (no builtin on gfx950)
__device__ __forceinline__ unsigned cvtpk(float lo, float hi) {
    unsigned r;
    asm("v_cvt_pk_bf16_f32 %0, %1, %2" : "=v"(r) : "v"(lo), "v"(hi));
    return r;
}

template<int CTRL>
__device__ __forceinline__ float dpp_add(float v) {
    int o = __builtin_amdgcn_mov_dpp(__float_as_int(v), CTRL, 0xf, 0xf, true);
    return v + __int_as_float(o);
}
__device__ __forceinline__ float row16_sum(float v) {
    v = dpp_add<0x128>(v);
    v = dpp_add<0x124>(v);
    v = dpp_add<0x122>(v);
    v = dpp_add<0x121>(v);
    return v;
}

// ---- cooperative stage: BYTES from global into LDS (linear, 16B/lane async) ----
template<int BYTES>
__device__ __forceinline__ void stage(const char* __restrict__ gsrc, char* ldsdst, int t) {
    const int wu = (t >> 6) << 10;   // wave-uniform LDS base offset (HW adds lane*16)
#pragma unroll
    for (int i = 0; i < BYTES / 4096; ++i)
        __builtin_amdgcn_global_load_lds(
            (const __attribute__((address_space(1))) void*)(gsrc + i * 4096 + t * 16),
            (__attribute__((address_space(3))) void*)(ldsdst + i * 4096 + wu),
            16, 0, 0);
}

// ---- flat accumulator file: acc[f] = row-frag0, acc[8+f] = row-frag1 ----
template<int NF>
__device__ __forceinline__ void init_acc(f32x4* acc, const float* __restrict__ bias, int c) {
#pragma unroll
    for (int f = 0; f < NF; ++f) {
        const float bv = bias[f * 16 + c];
        acc[f]     = (f32x4){bv, bv, bv, bv};
        acc[8 + f] = (f32x4){bv, bv, bv, bv};
    }
}
__device__ __forceinline__ void init_b3(f32x4& a0, f32x4& a1, const float* __restrict__ b3, int c) {
    const float bv = (c < 3) ? b3[c] : 0.f;
    a0 = (f32x4){bv, bv, bv, bv};
    a1 = (f32x4){bv, bv, bv, bv};
}

// ---- A fragment from xyz registers (k=0..2 hi, k=3..5 lo of the bf16 split) ----
__device__ __forceinline__ bf16x8 mkA6(float a0, float a1, float a2, bool active) {
    bf16x8 A = (bf16x8){0, 0, 0, 0, 0, 0, 0, 0};
    if (active) {
        const short h0 = bf1(a0), h1 = bf1(a1), h2 = bf1(a2);
        A[0] = h0; A[1] = h1; A[2] = h2;
        A[3] = bf1(a0 - bfval(h0));
        A[4] = bf1(a1 - bfval(h1));
        A[5] = bf1(a2 - bfval(h2));
    }
    return A;
}

// ---- MFMA with A from registers (single K-step), B frags from global ----
template<int NF>
__device__ __forceinline__ void mfma_reg(bf16x8 A0, bf16x8 A1, const char* __restrict__ Bg,
                                         int lane, f32x4* acc) {
#pragma unroll
    for (int f = 0; f < NF; ++f) {
        bf16x8 B = *(const bf16x8*)(Bg + f * 1024 + lane * 16);
        acc[f]     = __builtin_amdgcn_mfma_f32_16x16x32_bf16(A0, B, acc[f], 0, 0, 0);
        acc[8 + f] = __builtin_amdgcn_mfma_f32_16x16x32_bf16(A1, B, acc[8 + f], 0, 0, 0);
    }
}

// ---- staged MFMA layer: B frags double-buffered through LDS wb (2 x 8KB halves).
//      chunk0 must already be staged into wb[0] by the caller (prefetch). ----
template<int NF, int KS>
__device__ __forceinline__ void mfma_staged(const char* actb, char* wb,
                                            const char* __restrict__ Bg,
                                            int R0c, int g, int lane, int t, f32x4* acc) {
    constexpr int CH = NF * 1024;
    const int swz = (R0c & 7) << 4;
    __syncthreads();                      // drain prefetched chunk0
#pragma unroll
    for (int ks = 0; ks < KS; ++ks) {
        if (ks + 1 < KS)
            stage<CH>(Bg + (ks + 1) * CH, wb + ((ks + 1) & 1) * 8192, t);
        const char* cur = wb + (ks & 1) * 8192;
        const int kb = ks * 64 + g * 16;
        bf16x8 A0 = *(const bf16x8*)(actb + ((R0c * 256 + kb) ^ swz));
        bf16x8 A1 = *(const bf16x8*)(actb + (((R0c + 16) * 256 + kb) ^ swz));
#pragma unroll
        for (int f = 0; f < NF; ++f) {
            bf16x8 B = *(const bf16x8*)(cur + f * 1024 + lane * 16);
            acc[f]     = __builtin_amdgcn_mfma_f32_16x16x32_bf16(A0, B, acc[f], 0, 0, 0);
            acc[8 + f] = __builtin_amdgcn_mfma_f32_16x16x32_bf16(A1, B, acc[8 + f], 0, 0, 0);
        }
        __syncthreads();                  // next chunk staged & everyone done with cur
    }
}

// ---- N=3 projection (K=64, KS=2), unstaged ----
__device__ __forceinline__ void mfma3(const char* actb, const char* __restrict__ Bg,
                                      int R0c, int g, int lane, f32x4& a0, f32x4& a1) {
    const int swz = (R0c & 7) << 4;
#pragma unroll
    for (int ks = 0; ks < 2; ++ks) {
        const int kb = ks * 64 + g * 16;
        bf16x8 A0 = *(const bf16x8*)(actb + ((R0c * 256 + kb) ^ swz));
        bf16x8 A1 = *(const bf16x8*)(actb + (((R0c + 16) * 256 + kb) ^ swz));
        bf16x8 B = *(const bf16x8*)(Bg + ks * 1024 + lane * 16);
        a0 = __builtin_amdgcn_mfma_f32_16x16x32_bf16(A0, B, a0, 0, 0, 0);
        a1 = __builtin_amdgcn_mfma_f32_16x16x32_bf16(A1, B, a1, 0, 0, 0);
    }
}

// ---- LayerNorm + LeakyReLU, vectorized over the 4 row-quads; fma-folded apply ----
template<int NF>
__device__ __forceinline__ void ln_lrelu_frag(f32x4* acc, int c,
                                              const float* __restrict__ g,
                                              const float* __restrict__ be, float invN) {
    float gv[NF], bev[NF];
#pragma unroll
    for (int f = 0; f < NF; ++f) { gv[f] = g[f * 16 + c]; bev[f] = be[f * 16 + c]; }
#pragma unroll
    for (int rf = 0; rf < 2; ++rf) {
        f32x4 s1 = acc[rf * 8];
        f32x4 s2 = acc[rf * 8] * acc[rf * 8];
#pragma unroll
        for (int f = 1; f < NF; ++f) {
            s1 += acc[rf * 8 + f];
            s2 += acc[rf * 8 + f] * acc[rf * 8 + f];
        }
#pragma unroll
        for (int q = 0; q < 4; ++q) { s1[q] = row16_sum(s1[q]); s2[q] = row16_sum(s2[q]); }
        const f32x4 mu = s1 * invN;
        f32x4 ri;
#pragma unroll
        for (int q = 0; q < 4; ++q)
            ri[q] = rsqrtf(fmaf(s2[q], invN, -mu[q] * mu[q]) + 1e-5f);
        const f32x4 nmuri = -mu * ri;     // x_hat = fma(x, ri, nmuri)
#pragma unroll
        for (int f = 0; f < NF; ++f) {
            f32x4 xh = acc[rf * 8 + f] * ri + nmuri;
            f32x4 x = xh * gv[f] + bev[f];
            acc[rf * 8 + f] = __builtin_elementwise_max(x, 0.2f * x);
        }
    }
}

// ---- pack to LDS act tile. Storage map (dword D within row, lane c):
//   NF=8: D = c*4+d holds cols (d*16+c, (d+4)*16+c)   -> one b128/row/thread
//   NF=4: D = c*2+d holds cols (d*16+c, (d+2)*16+c)   -> one b64/row/thread
//  (B fragments are built with the matching k-map in wfrag) ----
template<int NF>
__device__ __forceinline__ void pack_store(char* dst, f32x4* acc, int R0, int c, int g) {
#pragma unroll
    for (int rf = 0; rf < 2; ++rf)
#pragma unroll
        for (int q = 0; q < 4; ++q) {
            const int row = R0 + rf * 16 + g * 4 + q;
            const int swz = (row & 7) << 4;
            if constexpr (NF == 8) {
                u32x4 v;
                v.x = cvtpk(acc[rf * 8 + 0][q], acc[rf * 8 + 4][q]);
                v.y = cvtpk(acc[rf * 8 + 1][q], acc[rf * 8 + 5][q]);
                v.z = cvtpk(acc[rf * 8 + 2][q], acc[rf * 8 + 6][q]);
                v.w = cvtpk(acc[rf * 8 + 3][q], acc[rf * 8 + 7][q]);
                *(u32x4*)(dst + ((row * 256 + c * 16) ^ swz)) = v;
            } else {
                u32x2 v;
                v.x = cvtpk(acc[rf * 8 + 0][q], acc[rf * 8 + 2][q]);
                v.y = cvtpk(acc[rf * 8 + 1][q], acc[rf * 8 + 3][q]);
                *(u32x2*)(dst + ((row * 256 + c * 8) ^ swz)) = v;
            }
        }
}

// ---------------- prep kernels ----------------

__global__ void ce_precompute_kernel(const int* __restrict__ cats,
                                     const float* __restrict__ cat_emb,
                                     const float* __restrict__ cr_w1,
                                     const float* __restrict__ cr_b1,
                                     float* __restrict__ ce_out) {
    const int bb = blockIdx.x;
    const int j = threadIdx.x;            // 0..127
    const int c = cats[bb];
    float acc = cr_b1[j];
#pragma unroll 4
    for (int k = 0; k < 128; ++k)
        acc = fmaf(cat_emb[c * 128 + k], cr_w1[(128 + k) * 128 + j], acc);
    ce_out[bb * 128 + j] = acc;
}

// build all B-fragments, ks-major; k-maps match the b128/b64 act storage:
//   mode 1 (128-col input): k = ((e>>1) + 4*(e&1))*16 + ks*4 + g
//   mode 2 (64-col input) : k = ((e>>1 & 1) + 2*(e&1))*16 + ks*8 + g*2 + (e>>2)
//   mode 0 (register A)   : k = p (identity, only k<6 nonzero)
__global__ void wfrag_kernel(
    const float* __restrict__ pr_w1, const float* __restrict__ pr_w2,
    const float* __restrict__ cr_w1, const float* __restrict__ cr_w2,
    const float* __restrict__ cr_w3, const float* __restrict__ sy_w1,
    const float* __restrict__ sy_w2, const float* __restrict__ sp_w1,
    const float* __restrict__ sp_w2, const float* __restrict__ sp_w3,
    char* __restrict__ ws)
{
    const int id = blockIdx.x * 256 + threadIdx.x;   // 0..22783 frag-lanes
    int local, NF, base, cat = 0;
    const float* W = nullptr;
    int mode;
    int Nstride = 0;

    if (id < 512)        { local = id;          NF = 8; base = WS_PR1; W = pr_w1; mode = 0; Nstride = 128; }
    else if (id < 2560)  { local = id - 512;    NF = 8; base = WS_PR2; W = pr_w2; mode = 1; Nstride = 128; }
    else if (id < 4608)  { local = id - 2560;   NF = 8; base = WS_CR1; W = cr_w1; mode = 1; Nstride = 128; }
    else if (id < 5632)  { local = id - 4608;   NF = 4; base = WS_CR2; W = cr_w2; mode = 1; Nstride = 64; }
    else if (id < 5760)  { local = id - 5632;   NF = 1; base = WS_CR3; W = cr_w3; mode = 2; }
    else if (id < 6016)  { local = id - 5760;   NF = 4; base = WS_SY1; W = sy_w1; mode = 0; Nstride = 64; }
    else if (id < 6144)  { local = id - 6016;   NF = 1; base = WS_SY2; W = sy_w2; mode = 2; }
    else if (id < 11264) { int r = id - 6144;  cat = r / 512;  local = r % 512;
                           NF = 8; base = WS_SP1 + cat * 8192;  W = sp_w1 + cat * 384;  mode = 0; Nstride = 128; }
    else if (id < 21504) { int r = id - 11264; cat = r / 1024; local = r % 1024;
                           NF = 4; base = WS_SP2 + cat * 16384; W = sp_w2 + cat * 8192; mode = 1; Nstride = 64; }
    else                 { int r = id - 21504; cat = r / 128;  local = r % 128;
                           NF = 1; base = WS_SP3 + cat * 2048;  W = sp_w3 + cat * 192;  mode = 2; }

    const int lane = local & 63;
    const int fk = local >> 6;
    const int f = fk % NF;              // ks-major: chunk = all f of one ks
    const int ks = fk / NF;
    const int c = lane & 15;
    const int g = lane >> 4;
    const int n = f * 16 + c;

    bf16x8 H;
#pragma unroll
    for (int e = 0; e < 8; ++e) {
        float v = 0.f;
        if (mode == 0) {
            const int p = ks * 32 + g * 8 + e;
            if (p < 6) v = W[(p < 3 ? p : p - 3) * Nstride + n];
        } else if (mode == 1) {
            const int k = ((e >> 1) + 4 * (e & 1)) * 16 + ks * 4 + g;
            v = W[k * Nstride + n];
        } else {
            const int k = (((e >> 1) & 1) + 2 * (e & 1)) * 16 + ks * 8 + g * 2 + (e >> 2);
            if (n < 3) v = W[k * 3 + n];
        }
        H[e] = bf1(v);
    }
    *(bf16x8*)(ws + base + local * 16) = H;
}

// ---------------- main fused kernel ----------------

__global__ __launch_bounds__(NT, 3)
void shape_refine_mfma14(
    const float* __restrict__ points, const int* __restrict__ cats,
    const float* __restrict__ pr_b1, const float* __restrict__ pr_g1, const float* __restrict__ pr_be1,
    const float* __restrict__ pr_b2, const float* __restrict__ pr_g2, const float* __restrict__ pr_be2,
    const float* __restrict__ cr_g1, const float* __restrict__ cr_be1,
    const float* __restrict__ cr_b2, const float* __restrict__ cr_g2, const float* __restrict__ cr_be2,
    const float* __restrict__ cr_b3,
    const float* __restrict__ sy_b1, const float* __restrict__ sy_g1, const float* __restrict__ sy_be1,
    const float* __restrict__ sy_b2,
    const float* __restrict__ sp_b1, const float* __restrict__ sp_g1, const float* __restrict__ sp_be1,
    const float* __restrict__ sp_b2, const float* __restrict__ sp_g2, const float* __restrict__ sp_be2,
    const float* __restrict__ sp_b3,
    const char* __restrict__ ws,
    float* __restrict__ out)
{
    __shared__ char act[32768];    // bf16 [128 rows][128 cols]; rows R0..R0+31 private to wave wid
    __shared__ char wb[16384];     // B-frag staging, 2 x 8KB halves

    const int t = threadIdx.x;
    const int lane = t & 63;
    const int wid = t >> 6;
    const int c = lane & 15;
    const int g = lane >> 4;
    const int R0 = wid * 32;
    const int R0c = R0 + c;

    const int bid = blockIdx.x;
    const int batch = bid >> 6;              // 64 blocks (tiles) per batch
    const int pbase = batch * 8192 + (bid & 63) * 128;

    const int cat = __builtin_amdgcn_readfirstlane(cats[batch]);
    const bool sym = (cat == 2) || (cat == 8);

    // prefetch P2 chunk0 under P1's compute
    stage<8192>(ws + WS_PR2, wb, t);

    // xyz for this lane's two A-rows (rows R0c and R0c+16)
    const float* p0 = points + 3 * (pbase + R0c);
    const float x0 = p0[0], x1 = p0[1], x2 = p0[2];
    const float y0 = p0[48], y1 = p0[49], y2 = p0[50];

    const bf16x8 A0 = mkA6(x0, x1, x2, g == 0);
    const bf16x8 A1 = mkA6(y0, y1, y2, g == 0);

    f32x4 acc[16];
    f32x4 ocr0, ocr1, oo0, oo1;

    // ---- P1: pr1 (3->128) from registers ----
    init_acc<8>(acc, pr_b1, c);
    mfma_reg<8>(A0, A1, ws + WS_PR1, lane, acc);
    ln_lrelu_frag<8>(acc, c, pr_g1, pr_be1, 1.f / 128.f);
    pack_store<8>(act, acc, R0, c, g);

    // ---- P2: pr2 (128->128), staged ----
    init_acc<8>(acc, pr_b2, c);
    mfma_staged<8, 4>(act, wb, ws + WS_PR2, R0c, g, lane, t, acc);
    stage<8192>(ws + WS_CR1, wb, t);            // prefetch P3 chunk0 under LN
    ln_lrelu_frag<8>(acc, c, pr_g2, pr_be2, 1.f / 128.f);
    pack_store<8>(act, acc, R0, c, g);

    // ---- P3: cr1 (256->128, cat-emb folded into per-batch bias), staged ----
    init_acc<8>(acc, (const float*)(ws + WS_CE) + batch * 128, c);
    mfma_staged<8, 4>(act, wb, ws + WS_CR1, R0c, g, lane, t, acc);
    stage<4096>(ws + WS_CR2, wb, t);            // prefetch P4 chunk0 under LN
    ln_lrelu_frag<8>(acc, c, cr_g1, cr_be1, 1.f / 128.f);
    pack_store<8>(act, acc, R0, c, g);

    // ---- P4: cr2 (128->64), staged ----
    init_acc<4>(acc, cr_b2, c);
    mfma_staged<4, 4>(act, wb, ws + WS_CR2, R0c, g, lane, t, acc);
    stage<4096>(ws + WS_SP2 + cat * 16384, wb, t);  // prefetch P6 chunk0 under P4-LN + P5
    ln_lrelu_frag<4>(acc, c, cr_g2, cr_be2, 1.f / 64.f);
    pack_store<4>(act, acc, R0, c, g);

    // ---- P5: cr3 (64->3) + sp1 (3->128) ----
    init_b3(ocr0, ocr1, cr_b3, c);
    mfma3(act, ws + WS_CR3, R0c, g, lane, ocr0, ocr1);

    init_acc<8>(acc, sp_b1 + cat * 128, c);
    mfma_reg<8>(A0, A1, ws + WS_SP1 + cat * 8192, lane, acc);
    ln_lrelu_frag<8>(acc, c, sp_g1 + cat * 128, sp_be1 + cat * 128, 1.f / 128.f);
    pack_store<8>(act, acc, R0, c, g);

    // ---- P6: sp2 (128->64), staged ----
    init_acc<4>(acc, sp_b2 + cat * 64, c);
    mfma_staged<4, 4>(act, wb, ws + WS_SP2 + cat * 16384, R0c, g, lane, t, acc);
    ln_lrelu_frag<4>(acc, c, sp_g2 + cat * 64, sp_be2 + cat * 64, 1.f / 64.f);
    pack_store<4>(act, acc, R0, c, g);

    // ---- P7: sp3 (64->3), combine ----
    init_b3(oo0, oo1, sp_b3 + cat * 3, c);
    mfma3(act, ws + WS_SP3 + cat * 2048, R0c, g, lane, oo0, oo1);
    oo0 = ocr0 + 0.5f * oo0;
    oo1 = ocr1 + 0.5f * oo1;

    // ---- symmetry branch (block-uniform) ----
    if (sym) {
        init_acc<4>(acc, sy_b1, c);
        const bf16x8 S0 = mkA6(-x0, x1, x2, g == 0);
        const bf16x8 S1 = mkA6(-y0, y1, y2, g == 0);
        mfma_reg<4>(S0, S1, ws + WS_SY1, lane, acc);
        ln_lrelu_frag<4>(acc, c, sy_g1, sy_be1, 1.f / 64.f);
        pack_store<4>(act, acc, R0, c, g);
        f32x4 s0, s1;
        init_b3(s0, s1, sy_b2, c);
        mfma3(act, ws + WS_SY2, R0c, g, lane, s0, s1);
        const float flip = (c == 0) ? -1.f : 1.f;
#pragma unroll
        for (int q = 0; q < 4; ++q) {
            oo0[q] = (oo0[q] + flip * s0[q]) * 0.5f;
            oo1[q] = (oo1[q] + flip * s1[q]) * 0.5f;
        }
    }

    // ---- store: lane c<3 holds dim c for rows R0 + g*4+q and +16 ----
    if (c < 3) {
#pragma unroll
        for (int q = 0; q < 4; ++q) {
            const int row0 = R0 + g * 4 + q;
            out[3 * (pbase + row0) + c] = oo0[q];
            out[3 * (pbase + row0 + 16) + c] = oo1[q];
        }
    }
}

// ---------------- launch ----------------

extern "C" void kernel_launch(void* const* d_in, const int* in_sizes, int n_in,
                              void* d_out, int out_size, void* d_ws, size_t ws_size,
                              hipStream_t stream) {
    const float* points  = (const float*)d_in[0];
    const int*   cats    = (const int*)  d_in[1];
    const float* pr_w1   = (const float*)d_in[2];
    const float* pr_b1   = (const float*)d_in[3];
    const float* pr_g1   = (const float*)d_in[4];
    const float* pr_be1  = (const float*)d_in[5];
    const float* pr_w2   = (const float*)d_in[6];
    const float* pr_b2   = (const float*)d_in[7];
    const float* pr_g2   = (const float*)d_in[8];
    const float* pr_be2  = (const float*)d_in[9];
    const float* cat_emb = (const float*)d_in[10];
    const float* cr_w1   = (const float*)d_in[11];
    const float* cr_b1   = (const float*)d_in[12];
    const float* cr_g1   = (const float*)d_in[13];
    const float* cr_be1  = (const float*)d_in[14];
    const float* cr_w2   = (const float*)d_in[15];
    const float* cr_b2   = (const float*)d_in[16];
    const float* cr_g2   = (const float*)d_in[17];
    const float* cr_be2  = (const float*)d_in[18];
    const float* cr_w3   = (const float*)d_in[19];
    const float* cr_b3   = (const float*)d_in[20];
    const float* sy_w1   = (const float*)d_in[21];
    const float* sy_b1   = (const float*)d_in[22];
    const float* sy_g1   = (const float*)d_in[23];
    const float* sy_be1  = (const float*)d_in[24];
    const float* sy_w2   = (const float*)d_in[25];
    const float* sy_b2   = (const float*)d_in[26];
    const float* sp_w1   = (const float*)d_in[27];
    const float* sp_b1   = (const float*)d_in[28];
    const float* sp_g1   = (const float*)d_in[29];
    const float* sp_be1  = (const float*)d_in[30];
    const float* sp_w2   = (const float*)d_in[31];
    const float* sp_b2   = (const float*)d_in[32];
    const float* sp_g2   = (const float*)d_in[33];
    const float* sp_be2  = (const float*)d_in[34];
    const float* sp_w3   = (const float*)d_in[35];
    const float* sp_b3   = (const float*)d_in[36];

    char* ws = (char*)d_ws;
    float* out = (float*)d_out;

    ce_precompute_kernel<<<dim3(32), dim3(128), 0, stream>>>(cats, cat_emb, cr_w1, cr_b1, (float*)ws);
    wfrag_kernel<<<dim3(89), dim3(256), 0, stream>>>(pr_w1, pr_w2, cr_w1, cr_w2, cr_w3,
                                                     sy_w1, sy_w2, sp_w1, sp_w2, sp_w3, ws);

    shape_refine_mfma14<<<dim3(2048), dim3(NT), 0, stream>>>(
        points, cats,
        pr_b1, pr_g1, pr_be1,
        pr_b2, pr_g2, pr_be2,
        cr_g1, cr_be1,
        cr_b2, cr_g2, cr_be2,
        cr_b3,
        sy_b1, sy_g1, sy_be1, sy_b2,
        sp_b1, sp_g1, sp_be1,
        sp_b2, sp_g2, sp_be2,
        sp_b3,
        ws, out);
}